// Round 12
// baseline (429.876 us; speedup 1.0000x reference)
//
#include <hip/hip_runtime.h>
#include <hip/hip_bf16.h>

// ---------------- types / constants ----------------
typedef __bf16 bf16_t;
typedef __bf16 bf16x8 __attribute__((ext_vector_type(8)));
typedef float f32x4 __attribute__((ext_vector_type(4)));

#define T_TOK 8192
#define D_IN  2048
#define D_BOT 512
#define MAXTILES 192   // up: >= 8192/64 + 56
#define MAXDTILES 200  // down: >= 16384/128 + 8 + 64

union U4B8 { uint4 u; bf16x8 b; };
__device__ __forceinline__ bf16x8 as_bf16x8(uint4 u) { U4B8 x; x.u = u; return x.b; }
__device__ __forceinline__ uint4 as_uint4(bf16x8 b) { U4B8 x; x.b = b; return x.u; }

typedef const __attribute__((address_space(1))) void gas_void;
typedef __attribute__((address_space(3))) void las_void;
__device__ __forceinline__ void async16(const void* g, void* l) {
    __builtin_amdgcn_global_load_lds((gas_void*)g, (las_void*)l, 16, 0, 0);
}

__device__ __forceinline__ uint4 ld_cvt8(const float* __restrict__ p) {
    f32x4 a0 = ((const f32x4*)p)[0];
    f32x4 a1 = ((const f32x4*)p)[1];
    bf16x8 v;
    v[0] = (bf16_t)a0[0]; v[1] = (bf16_t)a0[1]; v[2] = (bf16_t)a0[2]; v[3] = (bf16_t)a0[3];
    v[4] = (bf16_t)a1[0]; v[5] = (bf16_t)a1[1]; v[6] = (bf16_t)a1[2]; v[7] = (bf16_t)a1[3];
    return as_uint4(v);
}

__device__ __forceinline__ float gelu_f(float v) {
    return 0.5f * v * (1.0f + erff(v * 0.7071067811865476f));
}

__global__ __launch_bounds__(256) void cvt_kernel(const float* __restrict__ src,
                                                  bf16_t* __restrict__ dst, int n8) {
    const int i = blockIdx.x * 256 + threadIdx.x;
    if (i < n8) ((uint4*)dst)[i] = ld_cvt8(src + (size_t)i * 8);
}

// ---------------- gate body (shared by standalone and fused kernels) ----------------
__device__ __forceinline__ void gate_body(int bid,
                                          const float* __restrict__ x,
                                          const float* __restrict__ gw,
                                          float* __restrict__ combine,
                                          int* __restrict__ sel,
                                          bf16_t* __restrict__ Xbf) {
    const int wave = threadIdx.x >> 6, lane = threadIdx.x & 63;
    const int t = bid * 4 + wave;
    const float* xrow = x + (size_t)t * D_IN;
    f32x4 xa[4][2];
#pragma unroll
    for (int c = 0; c < 4; ++c) {
        const float* p = xrow + c * 512 + lane * 8;
        xa[c][0] = ((const f32x4*)p)[0];
        xa[c][1] = ((const f32x4*)p)[1];
    }
#pragma unroll
    for (int c = 0; c < 4; ++c) {
        bf16x8 v;
#pragma unroll
        for (int j = 0; j < 4; ++j) { v[j] = (bf16_t)xa[c][0][j]; v[4 + j] = (bf16_t)xa[c][1][j]; }
        *(uint4*)(Xbf + (size_t)t * D_IN + c * 512 + lane * 8) = as_uint4(v);
    }
    float p[8];
#pragma unroll
    for (int e = 0; e < 8; ++e) {
        const float* gr = gw + e * D_IN;
        float s = 0.f;
#pragma unroll
        for (int c = 0; c < 4; ++c) {
            const float* q = gr + c * 512 + lane * 8;
            f32x4 g0 = ((const f32x4*)q)[0], g1 = ((const f32x4*)q)[1];
#pragma unroll
            for (int j = 0; j < 4; ++j) s += xa[c][0][j] * g0[j] + xa[c][1][j] * g1[j];
        }
#pragma unroll
        for (int off = 32; off > 0; off >>= 1) s += __shfl_xor(s, off, 64);
        p[e] = s;
    }
    float m = p[0];
#pragma unroll
    for (int e = 1; e < 8; ++e) m = fmaxf(m, p[e]);
    float sum = 0.f;
#pragma unroll
    for (int e = 0; e < 8; ++e) { p[e] = expf(p[e] - m); sum += p[e]; }
    const float inv = 1.0f / sum;
#pragma unroll
    for (int e = 0; e < 8; ++e) p[e] *= inv;
    int i0 = 0;
#pragma unroll
    for (int e = 1; e < 8; ++e) if (p[e] > p[i0]) i0 = e;
    int i1 = -1;
#pragma unroll
    for (int e = 0; e < 8; ++e) { if (e == i0) continue; if (i1 < 0 || p[e] > p[i1]) i1 = e; }
    const float rs = 1.0f / (p[i0] + p[i1]);
    if (lane < 8)
        combine[t * 8 + lane] = (lane == i0) ? p[i0] * rs : (lane == i1) ? p[i1] * rs : 0.0f;
    if (lane == 0) sel[t] = i0 | (i1 << 4);
}

__global__ __launch_bounds__(256) void gate_kernel(const float* __restrict__ x,
                                                   const float* __restrict__ gw,
                                                   float* __restrict__ combine,
                                                   int* __restrict__ sel,
                                                   bf16_t* __restrict__ Xbf) {
    gate_body(blockIdx.x, x, gw, combine, sel, Xbf);
}

// fused: blocks 0..2047 gate; 2048..11263 the four weight conversions (independent work)
__global__ __launch_bounds__(256) void gate_cvt_kernel(const float* __restrict__ x,
                                                       const float* __restrict__ gw,
                                                       float* __restrict__ combine,
                                                       int* __restrict__ sel,
                                                       bf16_t* __restrict__ Xbf,
                                                       const float* __restrict__ wd,
                                                       const float* __restrict__ wsd,
                                                       const float* __restrict__ wu,
                                                       const float* __restrict__ wsu,
                                                       bf16_t* __restrict__ WallD,
                                                       bf16_t* __restrict__ WallU) {
    if (blockIdx.x < 2048) { gate_body(blockIdx.x, x, gw, combine, sel, Xbf); return; }
    const int i = (blockIdx.x - 2048) * 256 + threadIdx.x;
    const int N0 = 4096 * 2048 / 8;          // wd
    const int N1 = N0 + 512 * 2048 / 8;      // wsd
    const int N2 = N1 + 8 * 2048 * 512 / 8;  // wu
    const int N3 = N2 + 2048 * 512 / 8;      // wsu
    if (i < N0)      ((uint4*)WallD)[i] = ld_cvt8(wd + (size_t)i * 8);
    else if (i < N1) ((uint4*)WallD)[i] = ld_cvt8(wsd + (size_t)(i - N0) * 8);
    else if (i < N2) ((uint4*)WallU)[i - N1] = ld_cvt8(wu + (size_t)(i - N1) * 8);
    else if (i < N3) ((uint4*)WallU)[i - N1] = ld_cvt8(wsu + (size_t)(i - N2) * 8);
}

// ---------------- deterministic list build: expert lists + pair bins + tile tables ----------------
// meta: cnt[0..7]; ntilesP@8; ntilesD@9; cntP[64]@64; tileP[192]@128; tileS[192]@320;
//       tileDe[200]@512; tileDs[200]@768
__global__ __launch_bounds__(256) void build_kernel(const int* __restrict__ sel,
                                                    int* __restrict__ meta,
                                                    int* __restrict__ tokE,
                                                    int* __restrict__ tokP) {
    __shared__ unsigned short cAll[8][256];
    __shared__ unsigned short cP[64][256];
    const int tid = threadIdx.x;
#pragma unroll
    for (int e = 0; e < 8; ++e) cAll[e][tid] = 0;
#pragma unroll
    for (int p = 0; p < 64; ++p) cP[p][tid] = 0;
    __syncthreads();
    int sl[32];
#pragma unroll
    for (int j = 0; j < 32; ++j) sl[j] = sel[tid * 32 + j];
#pragma unroll
    for (int j = 0; j < 32; ++j) {
        const int e0 = sl[j] & 15, e1 = sl[j] >> 4;
        cAll[e0][tid]++; cAll[e1][tid]++; cP[e0 * 8 + e1][tid]++;
    }
    __syncthreads();
    if (tid < 8) {
        unsigned short* arr = cAll[tid];
        int run = 0;
        for (int i = 0; i < 256; ++i) { int v = arr[i]; arr[i] = (unsigned short)run; run += v; }
        meta[tid] = run;
    } else if (tid >= 64 && tid < 128) {
        unsigned short* arr = cP[tid - 64];
        int run = 0;
        for (int i = 0; i < 256; ++i) { int v = arr[i]; arr[i] = (unsigned short)run; run += v; }
        meta[64 + (tid - 64)] = run;
    }
    __syncthreads();
    if (tid == 0) {
        int nt = 0;
        for (int p = 0; p < 64; ++p) {
            const int c = meta[64 + p];
            for (int s = 0; s < c; s += 64) { meta[128 + nt] = p; meta[320 + nt] = s; ++nt; }
        }
        meta[8] = nt;
        // down-tile table: dense (expert, row-start) list so every launched block works
        int nd = 0;
        for (int e = 0; e < 9; ++e) {
            const int c = (e < 8) ? meta[e] : T_TOK;
            for (int s = 0; s < c; s += 128) { meta[512 + nd] = e; meta[768 + nd] = s; ++nd; }
        }
        meta[9] = nd;
    }
#pragma unroll
    for (int j = 0; j < 32; ++j) {
        const int t = tid * 32 + j, e0 = sl[j] & 15, e1 = sl[j] >> 4;
        const int p0 = cAll[e0][tid]++;  tokE[e0 * 8192 + p0] = t;           // rank 0
        const int p1 = cAll[e1][tid]++;  tokE[e1 * 8192 + p1] = t | 65536;   // rank 1
        const int q  = cP[e0 * 8 + e1][tid]++;  tokP[(e0 * 8 + e1) * 8192 + q] = t;
    }
}

// ---------------- sparse down: Ht[t][rank][:] = gelu(X[t]@W_e^T + b) * combine ----------------
// 1-D grid 800 = 200 m-tiles x 4 n-tiles (BN=128), XCD-chunked swizzle, n-fastest.
// BM=128, BN=128, BK=64. 512 threads = 8 waves (4m x 2n), 32 KB LDS (cap 5 blocks/CU,
// above the 4-block wave cap -> no occupancy loss). Mirrors the verified up BN-widening:
// barrier-drain pairs per unit work halve (800 vs 1600 blocks), per-wave MFMA:stage 16:4
// vs 8:3, A-tile re-read 4x vs 8x. All 800 blocks co-resident.
__global__ __launch_bounds__(512) void down_kernel(const bf16_t* __restrict__ Xbf,
                                                   const bf16_t* __restrict__ Wall,
                                                   const float* __restrict__ Bd,
                                                   const float* __restrict__ Bsd,
                                                   const float* __restrict__ combine,
                                                   const int* __restrict__ meta,
                                                   const int* __restrict__ tokE,
                                                   bf16_t* __restrict__ Ht) {
    __shared__ uint4 As4[128 * 8];   // 16 KB
    __shared__ uint4 Bs4[128 * 8];   // 16 KB
    const int orig = blockIdx.x;
    const int swz = (orig & 7) * 100 + (orig >> 3);   // XCD chunk map, 800 = 8*100
    const int yt = swz >> 2;                          // m-tile 0..199
    const int tile_n = (swz & 3) * 128;               // n-tile fastest
    if (yt >= meta[9]) return;
    const int e = meta[512 + yt];
    const int m0 = meta[768 + yt];
    const int count = (e < 8) ? meta[e] : T_TOK;
    const int tid = threadIdx.x, lane = tid & 63, wv = tid >> 6;  // wv 0..7
    const int wm = wv >> 1, wn = wv & 1;              // 4m x 2n: per-wave 32 rows x 64 cols
    const int gB = (lane & 7) ^ ((lane >> 3) & 7);

    const bf16_t* aAddr[2];
#pragma unroll
    for (int j = 0; j < 2; ++j) {
        const int rr = (wv * 2 + j) * 8 + (lane >> 3);            // 0..127
        int gi = m0 + rr; if (gi > count - 1) gi = count - 1;
        const int t = (e < 8) ? (tokE[e * 8192 + gi] & 0xFFFF) : gi;
        aAddr[j] = Xbf + (size_t)t * D_IN + gB * 8;
    }
    const bf16_t* bAddr[2];
#pragma unroll
    for (int j = 0; j < 2; ++j) {
        const int rr = (wv * 2 + j) * 8 + (lane >> 3);            // 0..127
        bAddr[j] = Wall + (size_t)(e * 512 + tile_n + rr) * D_IN + gB * 8;
    }

    f32x4 acc[2][4];
#pragma unroll
    for (int i = 0; i < 2; ++i)
#pragma unroll
        for (int j = 0; j < 4; ++j) acc[i][j] = (f32x4){0.f, 0.f, 0.f, 0.f};

    for (int kt = 0; kt < D_IN / 64; ++kt) {
        const int k0 = kt * 64;
#pragma unroll
        for (int j = 0; j < 2; ++j)
            async16(aAddr[j] + k0, &As4[(wv * 2 + j) * 64]);
#pragma unroll
        for (int j = 0; j < 2; ++j)
            async16(bAddr[j] + k0, &Bs4[(wv * 2 + j) * 64]);
        __syncthreads();
#pragma unroll
        for (int ks = 0; ks < 2; ++ks) {
            bf16x8 af[2], bfr[4];
#pragma unroll
            for (int i = 0; i < 2; ++i) {
                const int ar = wm * 32 + i * 16 + (lane & 15);
                af[i] = as_bf16x8(As4[ar * 8 + ((ks * 4 + (lane >> 4)) ^ (lane & 7))]);
            }
#pragma unroll
            for (int i = 0; i < 4; ++i) {
                const int br = wn * 64 + i * 16 + (lane & 15);
                bfr[i] = as_bf16x8(Bs4[br * 8 + ((ks * 4 + (lane >> 4)) ^ (lane & 7))]);
            }
#pragma unroll
            for (int mi = 0; mi < 2; ++mi)
#pragma unroll
                for (int nj = 0; nj < 4; ++nj)
                    acc[mi][nj] = __builtin_amdgcn_mfma_f32_16x16x32_bf16(
                        af[mi], bfr[nj], acc[mi][nj], 0, 0, 0);
        }
        __syncthreads();
    }

#pragma unroll
    for (int nj = 0; nj < 4; ++nj) {
        const int nn = tile_n + wn * 64 + nj * 16 + (lane & 15);   // 0..511
        const float bias = (e < 8) ? Bd[e * 512 + nn] : Bsd[nn];
#pragma unroll
        for (int mi = 0; mi < 2; ++mi) {
            const int g0 = m0 + wm * 32 + mi * 16 + ((lane >> 4) << 2);
#pragma unroll
            for (int r = 0; r < 4; ++r) {
                const int gi = g0 + r;
                if (gi >= count) continue;
                if (e < 8) {
                    const int entry = tokE[e * 8192 + gi];
                    const int t = entry & 0xFFFF, rank = entry >> 16;
                    const float v = gelu_f(acc[mi][nj][r] + bias) * combine[t * 8 + e];
                    Ht[(size_t)t * 1536 + rank * 512 + nn] = (bf16_t)v;
                } else {
                    Ht[(size_t)gi * 1536 + 1024 + nn] = (bf16_t)gelu_f(acc[mi][nj][r] + bias);
                }
            }
        }
    }
}

// ---------------- pair-grouped up: Out[t,:] = Ht[t,:]@B_pair^T + c@bu + bs_u (direct store) ----
// 1-D grid 1536 = 192 m-tiles x 8 n-tiles (BN=256), XCD-chunked swizzle, n-fastest.
// BM=64, BN=256, BK=64. 512 threads = 8 waves (2m x 4n), 40 KB LDS.
__global__ __launch_bounds__(512) void up_kernel(const bf16_t* __restrict__ Ht,
                                                 const bf16_t* __restrict__ Wup,
                                                 const float* __restrict__ Bu,
                                                 const float* __restrict__ Bsu,
                                                 const float* __restrict__ combine,
                                                 const int* __restrict__ meta,
                                                 const int* __restrict__ tokP,
                                                 float* __restrict__ Out) {
    __shared__ uint4 As4[64 * 8];    //  8 KB
    __shared__ uint4 Bs4[256 * 8];   // 32 KB
    const int orig = blockIdx.x;
    const int swz = (orig & 7) * 192 + (orig >> 3);   // XCD chunk map, 1536 = 8*192
    const int yt = swz >> 3;                          // m-tile 0..191
    const int tile_n = (swz & 7) * 256;               // n-tile fastest
    if (yt >= meta[8]) return;
    const int p = meta[128 + yt], s = meta[320 + yt];
    const int e0 = p >> 3, e1 = p & 7;
    const int cntP = meta[64 + p];
    const int tid = threadIdx.x, lane = tid & 63, wv = tid >> 6;  // wv 0..7
    const int wm = wv >> 2, wn = wv & 3;              // 2m x 4n
    const int gB = (lane & 7) ^ ((lane >> 3) & 7);

    const bf16_t* aAddr;
    {
        const int rr = wv * 8 + (lane >> 3);                      // 0..63
        int gi = s + rr; if (gi > cntP - 1) gi = cntP - 1;
        const int t = tokP[p * 8192 + gi];
        aAddr = Ht + (size_t)t * 1536 + gB * 8;
    }
    size_t bRow[4];
#pragma unroll
    for (int j = 0; j < 4; ++j) {
        const int rr = (wv * 4 + j) * 8 + (lane >> 3);            // 0..255
        bRow[j] = (size_t)(tile_n + rr) * D_BOT + gB * 8;
    }

    f32x4 acc[2][4];
#pragma unroll
    for (int i = 0; i < 2; ++i)
#pragma unroll
        for (int j = 0; j < 4; ++j) acc[i][j] = (f32x4){0.f, 0.f, 0.f, 0.f};

    for (int kt = 0; kt < 24; ++kt) {
        const int seg = kt >> 3;
        const int slot = (seg == 0) ? e0 : (seg == 1) ? e1 : 8;
        const bf16_t* wbase = Wup + (size_t)slot * (D_IN * D_BOT) + (kt & 7) * 64;
        async16(aAddr + kt * 64, &As4[wv * 64]);
#pragma unroll
        for (int j = 0; j < 4; ++j)
            async16(wbase + bRow[j], &Bs4[(wv * 4 + j) * 64]);
        __syncthreads();
#pragma unroll
        for (int ks = 0; ks < 2; ++ks) {
            bf16x8 af[2], bfr[4];
#pragma unroll
            for (int i = 0; i < 2; ++i) {
                const int ar = wm * 32 + i * 16 + (lane & 15);
                af[i] = as_bf16x8(As4[ar * 8 + ((ks * 4 + (lane >> 4)) ^ (lane & 7))]);
            }
#pragma unroll
            for (int i = 0; i < 4; ++i) {
                const int br = wn * 64 + i * 16 + (lane & 15);
                bfr[i] = as_bf16x8(Bs4[br * 8 + ((ks * 4 + (lane >> 4)) ^ (lane & 7))]);
            }
#pragma unroll
            for (int mi = 0; mi < 2; ++mi)
#pragma unroll
                for (int nj = 0; nj < 4; ++nj)
                    acc[mi][nj] = __builtin_amdgcn_mfma_f32_16x16x32_bf16(
                        af[mi], bfr[nj], acc[mi][nj], 0, 0, 0);
        }
        __syncthreads();
    }

#pragma unroll
    for (int nj = 0; nj < 4; ++nj) {
        const int d = tile_n + wn * 64 + nj * 16 + (lane & 15);    // 0..2047
        const float bu0 = Bu[e0 * D_IN + d], bu1 = Bu[e1 * D_IN + d], bs = Bsu[d];
#pragma unroll
        for (int mi = 0; mi < 2; ++mi) {
            const int r0 = wm * 32 + mi * 16 + ((lane >> 4) << 2);
#pragma unroll
            for (int r = 0; r < 4; ++r) {
                const int gi = s + r0 + r;
                if (gi >= cntP) continue;
                const int t = tokP[p * 8192 + gi];
                const float c0 = combine[t * 8 + e0], c1 = combine[t * 8 + e1];
                Out[(size_t)t * D_IN + d] = acc[mi][nj][r] + c0 * bu0 + c1 * bu1 + bs;
            }
        }
    }
}

// ---------------- launch ----------------
extern "C" void kernel_launch(void* const* d_in, const int* in_sizes, int n_in,
                              void* d_out, int out_size, void* d_ws, size_t ws_size,
                              hipStream_t stream) {
    const float* x   = (const float*)d_in[0];
    const float* gw  = (const float*)d_in[1];
    const float* wd  = (const float*)d_in[2];
    const float* bd  = (const float*)d_in[3];
    const float* wu  = (const float*)d_in[4];
    const float* bu  = (const float*)d_in[5];
    const float* wsd = (const float*)d_in[6];
    const float* bsd = (const float*)d_in[7];
    const float* wsu = (const float*)d_in[8];
    const float* bsu = (const float*)d_in[9];
    float* out = (float*)d_out;

    // workspace layout:
    char* ws = (char*)d_ws;
    float* combine = (float*)(ws + 0);                 // 262,144
    int*   meta    = (int*)(ws + 262144);              // 4 KB
    int*   sel     = (int*)(ws + 266240);              // 32,768
    int*   tokE    = (int*)(ws + 299008);              // 262,144
    int*   tokP    = (int*)(ws + 561152);              // 2,097,152
    bf16_t* Xbf    = (bf16_t*)(ws + 2658304);          // 33,554,432
    bf16_t* Ht     = (bf16_t*)(ws + 36212736ull);      // 25,165,824
    bf16_t* WallD  = (bf16_t*)(ws + 61378560ull);      // 18,874,368 (down weights)
    const size_t NEED_SEP = 61378560ull + 2ull * 18874368ull;  // 99,127,296
    const bool separate = (ws_size >= NEED_SEP);
    bf16_t* WallU  = separate ? (bf16_t*)(ws + 61378560ull + 18874368ull) : WallD;

    if (separate) {
        // gate + all weight conversions in ONE launch (independent work, overlapped)
        gate_cvt_kernel<<<2048 + 9216, 256, 0, stream>>>(x, gw, combine, sel, Xbf,
                                                         wd, wsd, wu, wsu, WallD, WallU);
        build_kernel<<<1, 256, 0, stream>>>(sel, meta, tokE, tokP);
        down_kernel<<<MAXDTILES * 4, 512, 0, stream>>>(Xbf, WallD, bd, bsd, combine, meta, tokE, Ht);
        up_kernel<<<MAXTILES * 8, 512, 0, stream>>>(Ht, WallU, bu, bsu, combine, meta, tokP, out);
    } else {
        // overlay fallback (original ordering)
        gate_kernel<<<T_TOK / 4, 256, 0, stream>>>(x, gw, combine, sel, Xbf);
        build_kernel<<<1, 256, 0, stream>>>(sel, meta, tokE, tokP);
        cvt_kernel<<<(4096 * D_IN / 8) / 256, 256, 0, stream>>>(wd, WallD, 4096 * D_IN / 8);
        cvt_kernel<<<(512 * D_IN / 8) / 256, 256, 0, stream>>>(wsd, WallD + (size_t)4096 * D_IN, 512 * D_IN / 8);
        down_kernel<<<MAXDTILES * 4, 512, 0, stream>>>(Xbf, WallD, bd, bsd, combine, meta, tokE, Ht);
        cvt_kernel<<<(8 * D_IN * D_BOT / 8) / 256, 256, 0, stream>>>(wu, WallD, 8 * D_IN * D_BOT / 8);
        cvt_kernel<<<(D_IN * D_BOT / 8) / 256, 256, 0, stream>>>(wsu, WallD + (size_t)8 * D_IN * D_BOT, D_IN * D_BOT / 8);
        up_kernel<<<MAXTILES * 8, 512, 0, stream>>>(Ht, WallD, bu, bsu, combine, meta, tokP, out);
    }
}

// Round 13
// 422.935 us; speedup vs baseline: 1.0164x; 1.0164x over previous
//
#include <hip/hip_runtime.h>
#include <hip/hip_bf16.h>

// ---------------- types / constants ----------------
typedef __bf16 bf16_t;
typedef __bf16 bf16x8 __attribute__((ext_vector_type(8)));
typedef float f32x4 __attribute__((ext_vector_type(4)));

#define T_TOK 8192
#define D_IN  2048
#define D_BOT 512
#define MAXTILES 192   // up: >= 8192/64 + 56
#define MAXDTILES 200  // down: >= 16384/128 + 8 + 64

union U4B8 { uint4 u; bf16x8 b; };
__device__ __forceinline__ bf16x8 as_bf16x8(uint4 u) { U4B8 x; x.u = u; return x.b; }
__device__ __forceinline__ uint4 as_uint4(bf16x8 b) { U4B8 x; x.b = b; return x.u; }

typedef const __attribute__((address_space(1))) void gas_void;
typedef __attribute__((address_space(3))) void las_void;
__device__ __forceinline__ void async16(const void* g, void* l) {
    __builtin_amdgcn_global_load_lds((gas_void*)g, (las_void*)l, 16, 0, 0);
}

__device__ __forceinline__ uint4 ld_cvt8(const float* __restrict__ p) {
    f32x4 a0 = ((const f32x4*)p)[0];
    f32x4 a1 = ((const f32x4*)p)[1];
    bf16x8 v;
    v[0] = (bf16_t)a0[0]; v[1] = (bf16_t)a0[1]; v[2] = (bf16_t)a0[2]; v[3] = (bf16_t)a0[3];
    v[4] = (bf16_t)a1[0]; v[5] = (bf16_t)a1[1]; v[6] = (bf16_t)a1[2]; v[7] = (bf16_t)a1[3];
    return as_uint4(v);
}

__device__ __forceinline__ float gelu_f(float v) {
    return 0.5f * v * (1.0f + erff(v * 0.7071067811865476f));
}

__global__ __launch_bounds__(256) void cvt_kernel(const float* __restrict__ src,
                                                  bf16_t* __restrict__ dst, int n8) {
    const int i = blockIdx.x * 256 + threadIdx.x;
    if (i < n8) ((uint4*)dst)[i] = ld_cvt8(src + (size_t)i * 8);
}

// ---------------- gate body (shared by standalone and fused kernels) ----------------
__device__ __forceinline__ void gate_body(int bid,
                                          const float* __restrict__ x,
                                          const float* __restrict__ gw,
                                          float* __restrict__ combine,
                                          int* __restrict__ sel,
                                          bf16_t* __restrict__ Xbf) {
    const int wave = threadIdx.x >> 6, lane = threadIdx.x & 63;
    const int t = bid * 4 + wave;
    const float* xrow = x + (size_t)t * D_IN;
    f32x4 xa[4][2];
#pragma unroll
    for (int c = 0; c < 4; ++c) {
        const float* p = xrow + c * 512 + lane * 8;
        xa[c][0] = ((const f32x4*)p)[0];
        xa[c][1] = ((const f32x4*)p)[1];
    }
#pragma unroll
    for (int c = 0; c < 4; ++c) {
        bf16x8 v;
#pragma unroll
        for (int j = 0; j < 4; ++j) { v[j] = (bf16_t)xa[c][0][j]; v[4 + j] = (bf16_t)xa[c][1][j]; }
        *(uint4*)(Xbf + (size_t)t * D_IN + c * 512 + lane * 8) = as_uint4(v);
    }
    float p[8];
#pragma unroll
    for (int e = 0; e < 8; ++e) {
        const float* gr = gw + e * D_IN;
        float s = 0.f;
#pragma unroll
        for (int c = 0; c < 4; ++c) {
            const float* q = gr + c * 512 + lane * 8;
            f32x4 g0 = ((const f32x4*)q)[0], g1 = ((const f32x4*)q)[1];
#pragma unroll
            for (int j = 0; j < 4; ++j) s += xa[c][0][j] * g0[j] + xa[c][1][j] * g1[j];
        }
#pragma unroll
        for (int off = 32; off > 0; off >>= 1) s += __shfl_xor(s, off, 64);
        p[e] = s;
    }
    float m = p[0];
#pragma unroll
    for (int e = 1; e < 8; ++e) m = fmaxf(m, p[e]);
    float sum = 0.f;
#pragma unroll
    for (int e = 0; e < 8; ++e) { p[e] = expf(p[e] - m); sum += p[e]; }
    const float inv = 1.0f / sum;
#pragma unroll
    for (int e = 0; e < 8; ++e) p[e] *= inv;
    int i0 = 0;
#pragma unroll
    for (int e = 1; e < 8; ++e) if (p[e] > p[i0]) i0 = e;
    int i1 = -1;
#pragma unroll
    for (int e = 0; e < 8; ++e) { if (e == i0) continue; if (i1 < 0 || p[e] > p[i1]) i1 = e; }
    const float rs = 1.0f / (p[i0] + p[i1]);
    if (lane < 8)
        combine[t * 8 + lane] = (lane == i0) ? p[i0] * rs : (lane == i1) ? p[i1] * rs : 0.0f;
    if (lane == 0) sel[t] = i0 | (i1 << 4);
}

__global__ __launch_bounds__(256) void gate_kernel(const float* __restrict__ x,
                                                   const float* __restrict__ gw,
                                                   float* __restrict__ combine,
                                                   int* __restrict__ sel,
                                                   bf16_t* __restrict__ Xbf) {
    gate_body(blockIdx.x, x, gw, combine, sel, Xbf);
}

// fused: blocks 0..2047 gate; 2048..11263 the four weight conversions (independent work)
__global__ __launch_bounds__(256) void gate_cvt_kernel(const float* __restrict__ x,
                                                       const float* __restrict__ gw,
                                                       float* __restrict__ combine,
                                                       int* __restrict__ sel,
                                                       bf16_t* __restrict__ Xbf,
                                                       const float* __restrict__ wd,
                                                       const float* __restrict__ wsd,
                                                       const float* __restrict__ wu,
                                                       const float* __restrict__ wsu,
                                                       bf16_t* __restrict__ WallD,
                                                       bf16_t* __restrict__ WallU) {
    if (blockIdx.x < 2048) { gate_body(blockIdx.x, x, gw, combine, sel, Xbf); return; }
    const int i = (blockIdx.x - 2048) * 256 + threadIdx.x;
    const int N0 = 4096 * 2048 / 8;          // wd
    const int N1 = N0 + 512 * 2048 / 8;      // wsd
    const int N2 = N1 + 8 * 2048 * 512 / 8;  // wu
    const int N3 = N2 + 2048 * 512 / 8;      // wsu
    if (i < N0)      ((uint4*)WallD)[i] = ld_cvt8(wd + (size_t)i * 8);
    else if (i < N1) ((uint4*)WallD)[i] = ld_cvt8(wsd + (size_t)(i - N0) * 8);
    else if (i < N2) ((uint4*)WallU)[i - N1] = ld_cvt8(wu + (size_t)(i - N1) * 8);
    else if (i < N3) ((uint4*)WallU)[i - N1] = ld_cvt8(wsu + (size_t)(i - N2) * 8);
}

// ---------------- deterministic list build: expert lists + pair bins + tile tables ----------------
// meta: cnt[0..7]; ntilesP@8; ntilesD@9; cntP[64]@64; tileP[192]@128; tileS[192]@320;
//       tileDe[200]@512; tileDs[200]@768
__global__ __launch_bounds__(256) void build_kernel(const int* __restrict__ sel,
                                                    int* __restrict__ meta,
                                                    int* __restrict__ tokE,
                                                    int* __restrict__ tokP) {
    __shared__ unsigned short cAll[8][256];
    __shared__ unsigned short cP[64][256];
    const int tid = threadIdx.x;
#pragma unroll
    for (int e = 0; e < 8; ++e) cAll[e][tid] = 0;
#pragma unroll
    for (int p = 0; p < 64; ++p) cP[p][tid] = 0;
    __syncthreads();
    int sl[32];
#pragma unroll
    for (int j = 0; j < 32; ++j) sl[j] = sel[tid * 32 + j];
#pragma unroll
    for (int j = 0; j < 32; ++j) {
        const int e0 = sl[j] & 15, e1 = sl[j] >> 4;
        cAll[e0][tid]++; cAll[e1][tid]++; cP[e0 * 8 + e1][tid]++;
    }
    __syncthreads();
    if (tid < 8) {
        unsigned short* arr = cAll[tid];
        int run = 0;
        for (int i = 0; i < 256; ++i) { int v = arr[i]; arr[i] = (unsigned short)run; run += v; }
        meta[tid] = run;
    } else if (tid >= 64 && tid < 128) {
        unsigned short* arr = cP[tid - 64];
        int run = 0;
        for (int i = 0; i < 256; ++i) { int v = arr[i]; arr[i] = (unsigned short)run; run += v; }
        meta[64 + (tid - 64)] = run;
    }
    __syncthreads();
    if (tid == 0) {
        int nt = 0;
        for (int p = 0; p < 64; ++p) {
            const int c = meta[64 + p];
            for (int s = 0; s < c; s += 64) { meta[128 + nt] = p; meta[320 + nt] = s; ++nt; }
        }
        meta[8] = nt;
        // down-tile table: dense (expert, row-start) list so every launched block works
        int nd = 0;
        for (int e = 0; e < 9; ++e) {
            const int c = (e < 8) ? meta[e] : T_TOK;
            for (int s = 0; s < c; s += 128) { meta[512 + nd] = e; meta[768 + nd] = s; ++nd; }
        }
        meta[9] = nd;
    }
#pragma unroll
    for (int j = 0; j < 32; ++j) {
        const int t = tid * 32 + j, e0 = sl[j] & 15, e1 = sl[j] >> 4;
        const int p0 = cAll[e0][tid]++;  tokE[e0 * 8192 + p0] = t;           // rank 0
        const int p1 = cAll[e1][tid]++;  tokE[e1 * 8192 + p1] = t | 65536;   // rank 1
        const int q  = cP[e0 * 8 + e1][tid]++;  tokP[(e0 * 8 + e1) * 8192 + q] = t;
    }
}

// ---------------- sparse down: Ht[t][rank][:] = gelu(X[t]@W_e^T + b) * combine ----------------
// 1-D grid 1600 = 200 m-tiles x 8 n-tiles, XCD-chunked swizzle, n-fastest.
// BM=128, BN=64, BK=64. 512 threads = 8 waves (4m x 2n), 24 KB LDS,
// single-buffer 2-barrier loop (verified best regime: max TLP, 0 bank conflicts).
__global__ __launch_bounds__(512) void down_kernel(const bf16_t* __restrict__ Xbf,
                                                   const bf16_t* __restrict__ Wall,
                                                   const float* __restrict__ Bd,
                                                   const float* __restrict__ Bsd,
                                                   const float* __restrict__ combine,
                                                   const int* __restrict__ meta,
                                                   const int* __restrict__ tokE,
                                                   bf16_t* __restrict__ Ht) {
    __shared__ uint4 As4[128 * 8];   // 16 KB
    __shared__ uint4 Bs4[64 * 8];    //  8 KB
    const int orig = blockIdx.x;
    const int swz = (orig & 7) * 200 + (orig >> 3);   // XCD chunk map, 1600 = 8*200
    const int yt = swz >> 3;                          // m-tile 0..199
    const int tile_n = (swz & 7) * 64;                // n-tile fastest
    if (yt >= meta[9]) return;
    const int e = meta[512 + yt];
    const int m0 = meta[768 + yt];
    const int count = (e < 8) ? meta[e] : T_TOK;
    const int tid = threadIdx.x, lane = tid & 63, wv = tid >> 6;  // wv 0..7
    const int wm = wv >> 1, wn = wv & 1;              // 4m x 2n
    const int gB = (lane & 7) ^ ((lane >> 3) & 7);

    const bf16_t* aAddr[2];
#pragma unroll
    for (int j = 0; j < 2; ++j) {
        const int rr = (wv * 2 + j) * 8 + (lane >> 3);            // 0..127
        int gi = m0 + rr; if (gi > count - 1) gi = count - 1;
        const int t = (e < 8) ? (tokE[e * 8192 + gi] & 0xFFFF) : gi;
        aAddr[j] = Xbf + (size_t)t * D_IN + gB * 8;
    }
    const bf16_t* bAddr;
    {
        const int rr = wv * 8 + (lane >> 3);                      // 0..63
        bAddr = Wall + (size_t)(e * 512 + tile_n + rr) * D_IN + gB * 8;
    }

    f32x4 acc[2][2];
#pragma unroll
    for (int i = 0; i < 2; ++i)
#pragma unroll
        for (int j = 0; j < 2; ++j) acc[i][j] = (f32x4){0.f, 0.f, 0.f, 0.f};

    for (int kt = 0; kt < D_IN / 64; ++kt) {
        const int k0 = kt * 64;
#pragma unroll
        for (int j = 0; j < 2; ++j)
            async16(aAddr[j] + k0, &As4[(wv * 2 + j) * 64]);
        async16(bAddr + k0, &Bs4[wv * 64]);
        __syncthreads();
#pragma unroll
        for (int ks = 0; ks < 2; ++ks) {
            bf16x8 af[2], bfr[2];
#pragma unroll
            for (int i = 0; i < 2; ++i) {
                const int ar = wm * 32 + i * 16 + (lane & 15);
                af[i] = as_bf16x8(As4[ar * 8 + ((ks * 4 + (lane >> 4)) ^ (lane & 7))]);
            }
#pragma unroll
            for (int i = 0; i < 2; ++i) {
                const int br = wn * 32 + i * 16 + (lane & 15);
                bfr[i] = as_bf16x8(Bs4[br * 8 + ((ks * 4 + (lane >> 4)) ^ (lane & 7))]);
            }
#pragma unroll
            for (int mi = 0; mi < 2; ++mi)
#pragma unroll
                for (int nj = 0; nj < 2; ++nj)
                    acc[mi][nj] = __builtin_amdgcn_mfma_f32_16x16x32_bf16(
                        af[mi], bfr[nj], acc[mi][nj], 0, 0, 0);
        }
        __syncthreads();
    }

#pragma unroll
    for (int nj = 0; nj < 2; ++nj) {
        const int nn = tile_n + wn * 32 + nj * 16 + (lane & 15);   // 0..511
        const float bias = (e < 8) ? Bd[e * 512 + nn] : Bsd[nn];
#pragma unroll
        for (int mi = 0; mi < 2; ++mi) {
            const int g0 = m0 + wm * 32 + mi * 16 + ((lane >> 4) << 2);
#pragma unroll
            for (int r = 0; r < 4; ++r) {
                const int gi = g0 + r;
                if (gi >= count) continue;
                if (e < 8) {
                    const int entry = tokE[e * 8192 + gi];
                    const int t = entry & 0xFFFF, rank = entry >> 16;
                    const float v = gelu_f(acc[mi][nj][r] + bias) * combine[t * 8 + e];
                    Ht[(size_t)t * 1536 + rank * 512 + nn] = (bf16_t)v;
                } else {
                    Ht[(size_t)gi * 1536 + 1024 + nn] = (bf16_t)gelu_f(acc[mi][nj][r] + bias);
                }
            }
        }
    }
}

// ---------------- pair-grouped up: Out[t,:] = Ht[t,:]@B_pair^T + c@bu + bs_u (direct store) ----
// 1-D grid 1536 = 192 m-tiles x 8 n-tiles (BN=256), XCD-chunked swizzle, n-fastest.
// BM=64, BN=256, BK=64. 512 threads = 8 waves (2m x 4n), 40 KB LDS.
__global__ __launch_bounds__(512) void up_kernel(const bf16_t* __restrict__ Ht,
                                                 const bf16_t* __restrict__ Wup,
                                                 const float* __restrict__ Bu,
                                                 const float* __restrict__ Bsu,
                                                 const float* __restrict__ combine,
                                                 const int* __restrict__ meta,
                                                 const int* __restrict__ tokP,
                                                 float* __restrict__ Out) {
    __shared__ uint4 As4[64 * 8];    //  8 KB
    __shared__ uint4 Bs4[256 * 8];   // 32 KB
    const int orig = blockIdx.x;
    const int swz = (orig & 7) * 192 + (orig >> 3);   // XCD chunk map, 1536 = 8*192
    const int yt = swz >> 3;                          // m-tile 0..191
    const int tile_n = (swz & 7) * 256;               // n-tile fastest
    if (yt >= meta[8]) return;
    const int p = meta[128 + yt], s = meta[320 + yt];
    const int e0 = p >> 3, e1 = p & 7;
    const int cntP = meta[64 + p];
    const int tid = threadIdx.x, lane = tid & 63, wv = tid >> 6;  // wv 0..7
    const int wm = wv >> 2, wn = wv & 3;              // 2m x 4n
    const int gB = (lane & 7) ^ ((lane >> 3) & 7);

    const bf16_t* aAddr;
    {
        const int rr = wv * 8 + (lane >> 3);                      // 0..63
        int gi = s + rr; if (gi > cntP - 1) gi = cntP - 1;
        const int t = tokP[p * 8192 + gi];
        aAddr = Ht + (size_t)t * 1536 + gB * 8;
    }
    size_t bRow[4];
#pragma unroll
    for (int j = 0; j < 4; ++j) {
        const int rr = (wv * 4 + j) * 8 + (lane >> 3);            // 0..255
        bRow[j] = (size_t)(tile_n + rr) * D_BOT + gB * 8;
    }

    f32x4 acc[2][4];
#pragma unroll
    for (int i = 0; i < 2; ++i)
#pragma unroll
        for (int j = 0; j < 4; ++j) acc[i][j] = (f32x4){0.f, 0.f, 0.f, 0.f};

    for (int kt = 0; kt < 24; ++kt) {
        const int seg = kt >> 3;
        const int slot = (seg == 0) ? e0 : (seg == 1) ? e1 : 8;
        const bf16_t* wbase = Wup + (size_t)slot * (D_IN * D_BOT) + (kt & 7) * 64;
        async16(aAddr + kt * 64, &As4[wv * 64]);
#pragma unroll
        for (int j = 0; j < 4; ++j)
            async16(wbase + bRow[j], &Bs4[(wv * 4 + j) * 64]);
        __syncthreads();
#pragma unroll
        for (int ks = 0; ks < 2; ++ks) {
            bf16x8 af[2], bfr[4];
#pragma unroll
            for (int i = 0; i < 2; ++i) {
                const int ar = wm * 32 + i * 16 + (lane & 15);
                af[i] = as_bf16x8(As4[ar * 8 + ((ks * 4 + (lane >> 4)) ^ (lane & 7))]);
            }
#pragma unroll
            for (int i = 0; i < 4; ++i) {
                const int br = wn * 64 + i * 16 + (lane & 15);
                bfr[i] = as_bf16x8(Bs4[br * 8 + ((ks * 4 + (lane >> 4)) ^ (lane & 7))]);
            }
#pragma unroll
            for (int mi = 0; mi < 2; ++mi)
#pragma unroll
                for (int nj = 0; nj < 4; ++nj)
                    acc[mi][nj] = __builtin_amdgcn_mfma_f32_16x16x32_bf16(
                        af[mi], bfr[nj], acc[mi][nj], 0, 0, 0);
        }
        __syncthreads();
    }

#pragma unroll
    for (int nj = 0; nj < 4; ++nj) {
        const int d = tile_n + wn * 64 + nj * 16 + (lane & 15);    // 0..2047
        const float bu0 = Bu[e0 * D_IN + d], bu1 = Bu[e1 * D_IN + d], bs = Bsu[d];
#pragma unroll
        for (int mi = 0; mi < 2; ++mi) {
            const int r0 = wm * 32 + mi * 16 + ((lane >> 4) << 2);
#pragma unroll
            for (int r = 0; r < 4; ++r) {
                const int gi = s + r0 + r;
                if (gi >= cntP) continue;
                const int t = tokP[p * 8192 + gi];
                const float c0 = combine[t * 8 + e0], c1 = combine[t * 8 + e1];
                Out[(size_t)t * D_IN + d] = acc[mi][nj][r] + c0 * bu0 + c1 * bu1 + bs;
            }
        }
    }
}

// ---------------- launch ----------------
extern "C" void kernel_launch(void* const* d_in, const int* in_sizes, int n_in,
                              void* d_out, int out_size, void* d_ws, size_t ws_size,
                              hipStream_t stream) {
    const float* x   = (const float*)d_in[0];
    const float* gw  = (const float*)d_in[1];
    const float* wd  = (const float*)d_in[2];
    const float* bd  = (const float*)d_in[3];
    const float* wu  = (const float*)d_in[4];
    const float* bu  = (const float*)d_in[5];
    const float* wsd = (const float*)d_in[6];
    const float* bsd = (const float*)d_in[7];
    const float* wsu = (const float*)d_in[8];
    const float* bsu = (const float*)d_in[9];
    float* out = (float*)d_out;

    // workspace layout:
    char* ws = (char*)d_ws;
    float* combine = (float*)(ws + 0);                 // 262,144
    int*   meta    = (int*)(ws + 262144);              // 4 KB
    int*   sel     = (int*)(ws + 266240);              // 32,768
    int*   tokE    = (int*)(ws + 299008);              // 262,144
    int*   tokP    = (int*)(ws + 561152);              // 2,097,152
    bf16_t* Xbf    = (bf16_t*)(ws + 2658304);          // 33,554,432
    bf16_t* Ht     = (bf16_t*)(ws + 36212736ull);      // 25,165,824
    bf16_t* WallD  = (bf16_t*)(ws + 61378560ull);      // 18,874,368 (down weights)
    const size_t NEED_SEP = 61378560ull + 2ull * 18874368ull;  // 99,127,296
    const bool separate = (ws_size >= NEED_SEP);
    bf16_t* WallU  = separate ? (bf16_t*)(ws + 61378560ull + 18874368ull) : WallD;

    if (separate) {
        // gate + all weight conversions in ONE launch (independent work, overlapped)
        gate_cvt_kernel<<<2048 + 9216, 256, 0, stream>>>(x, gw, combine, sel, Xbf,
                                                         wd, wsd, wu, wsu, WallD, WallU);
        build_kernel<<<1, 256, 0, stream>>>(sel, meta, tokE, tokP);
        down_kernel<<<MAXDTILES * 8, 512, 0, stream>>>(Xbf, WallD, bd, bsd, combine, meta, tokE, Ht);
        up_kernel<<<MAXTILES * 8, 512, 0, stream>>>(Ht, WallU, bu, bsu, combine, meta, tokP, out);
    } else {
        // overlay fallback (original ordering)
        gate_kernel<<<T_TOK / 4, 256, 0, stream>>>(x, gw, combine, sel, Xbf);
        build_kernel<<<1, 256, 0, stream>>>(sel, meta, tokE, tokP);
        cvt_kernel<<<(4096 * D_IN / 8) / 256, 256, 0, stream>>>(wd, WallD, 4096 * D_IN / 8);
        cvt_kernel<<<(512 * D_IN / 8) / 256, 256, 0, stream>>>(wsd, WallD + (size_t)4096 * D_IN, 512 * D_IN / 8);
        down_kernel<<<MAXDTILES * 8, 512, 0, stream>>>(Xbf, WallD, bd, bsd, combine, meta, tokE, Ht);
        cvt_kernel<<<(8 * D_IN * D_BOT / 8) / 256, 256, 0, stream>>>(wu, WallD, 8 * D_IN * D_BOT / 8);
        cvt_kernel<<<(D_IN * D_BOT / 8) / 256, 256, 0, stream>>>(wsu, WallD + (size_t)8 * D_IN * D_BOT, D_IN * D_BOT / 8);
        up_kernel<<<MAXTILES * 8, 512, 0, stream>>>(Ht, WallD, bu, bsu, combine, meta, tokP, out);
    }
}